// Round 1
// baseline (182.523 us; speedup 1.0000x reference)
//
#include <hip/hip_runtime.h>

#define NN 8192
#define DIN 128
#define DH 64
#define DOUT 16

typedef _Float16 half8 __attribute__((ext_vector_type(8)));
typedef float f32x4 __attribute__((ext_vector_type(4)));

// workspace layout (bytes)
#define OFF_SC   0u          // 4 x u32 scalar max-abs slots (X, Wi, Wo, H)
#define OFF_WIQ  256u        // Wi_int as f32 [128][64]    (32 KB)
#define OFF_WOQ  33280u      // Wo_int as f32 [64][16]     (4 KB)
#define OFF_YT   65536u      // Y^T f16 [64][8192]         (1 MB)  Y = Xq_int @ Wi_int, |Y|<=384
#define OFF_BITS 1114112u    // A>0 bitmask u32 [8192][256] (8 MB)
#define OFF_P1   9502720u    // h_int partials f32 [8][8192][64] (16 MB)
#define OFF_HF   26279936u   // h (dequant-scaled) f32 [8192][64] (2 MB)
#define OFF_RT   28377088u   // R^T f16 [16][8192] (256 KB) R = hq_int @ Wo_int, |R|<=192
#define OFF_P2   28639232u   // out_int partials f32 [8][8192][16] (4 MB)

__device__ __forceinline__ float getscale(const unsigned* sc, int idx, float qmax) {
  float s = __uint_as_float(sc[idx]) / qmax;
  return (s == 0.0f) ? 1.0f : s;   // matches reference: where(scale==0, 1, scale)
}

__global__ void k_init(unsigned* sc) {
  int t = threadIdx.x;
  if (t < 4) sc[t] = 0u;
}

__global__ __launch_bounds__(256) void k_scales(const float* __restrict__ X,
                                                const float* __restrict__ Wi,
                                                const float* __restrict__ Wo,
                                                unsigned* sc) {
  __shared__ float red[256];
  int t = threadIdx.x, b = blockIdx.x;
  float m = 0.0f;
  int slot;
  if (b < 64) {
    slot = 0;
    for (int i = b * 256 + t; i < NN * DIN; i += 64 * 256) m = fmaxf(m, fabsf(X[i]));
  } else if (b == 64) {
    slot = 1;
    for (int i = t; i < DIN * DH; i += 256) m = fmaxf(m, fabsf(Wi[i]));
  } else {
    slot = 2;
    for (int i = t; i < DH * DOUT; i += 256) m = fmaxf(m, fabsf(Wo[i]));
  }
  red[t] = m; __syncthreads();
  for (int s = 128; s > 0; s >>= 1) {
    if (t < s) red[t] = fmaxf(red[t], red[t + s]);
    __syncthreads();
  }
  if (t == 0) atomicMax(&sc[slot], __float_as_uint(red[0]));  // vals >= 0: uint cmp == float cmp
}

__global__ void k_quantW(const float* __restrict__ Wi, const float* __restrict__ Wo,
                         const unsigned* __restrict__ sc,
                         float* __restrict__ Wiq, float* __restrict__ Woq) {
  float swi = getscale(sc, 1, 1.0f);   // W_BIT=2 -> qmax=1
  float swo = getscale(sc, 2, 1.0f);
  int t = threadIdx.x;
  for (int i = t; i < DIN * DH; i += 256) {
    float q = rintf(Wi[i] / swi);                 // rintf == RNE == jnp.round
    Wiq[i] = fminf(fmaxf(q, -1.0f), 1.0f);
  }
  for (int i = t; i < DH * DOUT; i += 256) {
    float q = rintf(Wo[i] / swo);
    Woq[i] = fminf(fmaxf(q, -1.0f), 1.0f);
  }
}

// Y^T[j][k] = sum_n Xq_int[k][n] * Wi_int[n][j]   (exact small integers, |Y|<=384)
__global__ __launch_bounds__(256) void k_Y(const float* __restrict__ X,
                                           const float* __restrict__ Wiq,
                                           const unsigned* __restrict__ sc,
                                           _Float16* __restrict__ YT) {
  __shared__ float Xs[32][DIN];
  __shared__ float Ws[DIN][DH];
  float sx = getscale(sc, 0, 3.0f);   // ACT_BIT=3 -> qmax=3
  int t = threadIdx.x;
  int k0 = blockIdx.x * 32;
  for (int i = t; i < 32 * DIN; i += 256) {
    int r = i >> 7, c = i & 127;
    float q = rintf(X[(size_t)(k0 + r) * DIN + c] / sx);
    Xs[r][c] = fminf(fmaxf(q, -3.0f), 3.0f);
  }
  for (int i = t; i < DIN * DH; i += 256) Ws[i >> 6][i & 63] = Wiq[i];
  __syncthreads();
  int r = t >> 3, j0 = (t & 7) * 8;
  float acc[8] = {0, 0, 0, 0, 0, 0, 0, 0};
  for (int n = 0; n < DIN; ++n) {
    float xv = Xs[r][n];
#pragma unroll
    for (int jj = 0; jj < 8; ++jj) acc[jj] = fmaf(xv, Ws[n][j0 + jj], acc[jj]);
  }
  int k = k0 + r;
#pragma unroll
  for (int jj = 0; jj < 8; ++jj) YT[(size_t)(j0 + jj) * NN + k] = (_Float16)acc[jj];  // exact in f16
}

// GEMM1: h_int = Aq @ Y.  Reads A f32 ONCE (binarize fused), emits bitmask for gemm2.
// BM=128, BN=64, 4 waves (2x2), KSPLIT=8, BK=64. f16 MFMA, exact integer accumulate.
__global__ __launch_bounds__(256) void k_gemm1(const float* __restrict__ A,
                                               const _Float16* __restrict__ YT,
                                               unsigned* __restrict__ bits,
                                               float* __restrict__ P1) {
  __shared__ __align__(16) char As[128 * 128];  // f16 [128 rows][64 k], XOR-16 swizzled
  __shared__ __align__(16) char Bs[64 * 128];   // f16 [64 n-rows][64 k], same swizzle
  const int t = threadIdx.x;
  const int lane = t & 63;
  const int warp = t >> 6;
  const int wm = warp >> 1, wn = warp & 1;
  const int row0 = blockIdx.x * 128;
  const int split = blockIdx.y;
  const int k0base = split * (NN / 8);

  f32x4 acc[4][2] = {};

  const int ar = t >> 1, ah = t & 1;                       // A staging: row, 32-col half
  const float* arow = A + (size_t)(row0 + ar) * NN + ah * 32;
  unsigned* browbits = bits + (size_t)(row0 + ar) * (NN / 32) + ah;
  const int arow_sw = (ar & 7) << 4;

  const int bn = t >> 2, bp = t & 3;                       // B staging: row, 32B quarter
  const _Float16* brow = YT + (size_t)bn * NN + bp * 16;
  const int bn_sw = (bn & 7) << 4;

  const int l15 = lane & 15;
  const int koff = (((lane >> 4) << 4)) ^ ((lane & 7) << 4);  // kk=0 swizzled byte col

  for (int it = 0; it < (NN / 8) / 64; ++it) {
    const int k0 = k0base + it * 64;
    __syncthreads();
    {  // stage A: load 32 f32, binarize -> f16 {0,1} + bit word
      const float4* p = (const float4*)(arow + k0);
      float4 v[8];
#pragma unroll
      for (int j = 0; j < 8; ++j) v[j] = p[j];
      unsigned bw = 0u;
#pragma unroll
      for (int j = 0; j < 8; ++j) {
        bw |= (unsigned)(v[j].x > 0.0f) << (4 * j + 0);
        bw |= (unsigned)(v[j].y > 0.0f) << (4 * j + 1);
        bw |= (unsigned)(v[j].z > 0.0f) << (4 * j + 2);
        bw |= (unsigned)(v[j].w > 0.0f) << (4 * j + 3);
      }
#pragma unroll
      for (int g = 0; g < 4; ++g) {
        unsigned bb = bw >> (8 * g);
        uint4 w;
        w.x = ((bb & 1u)  ? 0x3C00u : 0u) | ((bb & 2u)   ? 0x3C000000u : 0u);
        w.y = ((bb & 4u)  ? 0x3C00u : 0u) | ((bb & 8u)   ? 0x3C000000u : 0u);
        w.z = ((bb & 16u) ? 0x3C00u : 0u) | ((bb & 32u)  ? 0x3C000000u : 0u);
        w.w = ((bb & 64u) ? 0x3C00u : 0u) | ((bb & 128u) ? 0x3C000000u : 0u);
        *(uint4*)(&As[ar * 128 + ((ah * 64 + g * 16) ^ arow_sw)]) = w;
      }
      browbits[(size_t)(k0 >> 5)] = bw;
    }
    {  // stage B (Y^T rows are already [n][k])
      const uint4* p = (const uint4*)(brow + k0);
      uint4 u0 = p[0], u1 = p[1];
      *(uint4*)(&Bs[bn * 128 + ((bp * 32) ^ bn_sw)]) = u0;
      *(uint4*)(&Bs[bn * 128 + ((bp * 32 + 16) ^ bn_sw)]) = u1;
    }
    __syncthreads();
#pragma unroll
    for (int kk = 0; kk < 2; ++kk) {
      half8 af[4], bf[2];
#pragma unroll
      for (int m = 0; m < 4; ++m)
        af[m] = *(const half8*)(&As[(wm * 64 + m * 16 + l15) * 128 + (koff ^ (kk << 6))]);
#pragma unroll
      for (int n = 0; n < 2; ++n)
        bf[n] = *(const half8*)(&Bs[(wn * 32 + n * 16 + l15) * 128 + (koff ^ (kk << 6))]);
#pragma unroll
      for (int m = 0; m < 4; ++m) {
#pragma unroll
        for (int n = 0; n < 2; ++n)
          acc[m][n] = __builtin_amdgcn_mfma_f32_16x16x32_f16(af[m], bf[n], acc[m][n], 0, 0, 0);
      }
    }
  }
  const int r4 = (lane >> 4) * 4;
#pragma unroll
  for (int m = 0; m < 4; ++m) {
#pragma unroll
    for (int n = 0; n < 2; ++n) {
#pragma unroll
      for (int i = 0; i < 4; ++i) {
        int rr = row0 + wm * 64 + m * 16 + r4 + i;
        int cc = wn * 32 + n * 16 + l15;
        P1[((size_t)split * NN + rr) * DH + cc] = acc[m][n][i];
      }
    }
  }
}

// reduce K-split partials -> h (scaled), global max|h|
__global__ __launch_bounds__(256) void k_h2(const float* __restrict__ P1,
                                            unsigned* sc, float* __restrict__ hf) {
  float sxw = getscale(sc, 0, 3.0f) * getscale(sc, 1, 1.0f);
  int e = blockIdx.x * 256 + threadIdx.x;  // < 8192*64
  float s = 0.0f;
#pragma unroll
  for (int sp = 0; sp < 8; ++sp) s += P1[(size_t)sp * NN * DH + e];  // exact integer adds
  float v = s * sxw;
  hf[e] = v;
  __shared__ float red[256];
  red[threadIdx.x] = fabsf(v); __syncthreads();
  for (int st = 128; st > 0; st >>= 1) {
    if (threadIdx.x < st) red[threadIdx.x] = fmaxf(red[threadIdx.x], red[threadIdx.x + st]);
    __syncthreads();
  }
  if (threadIdx.x == 0) atomicMax(&sc[3], __float_as_uint(red[0]));
}

// R^T[j][i] = sum_n hq_int[i][n] * Wo_int[n][j]   (|R|<=192, exact in f16)
__global__ __launch_bounds__(256) void k_R(const float* __restrict__ hf,
                                           const float* __restrict__ Woq,
                                           const unsigned* __restrict__ sc,
                                           _Float16* __restrict__ RT) {
  float sh = getscale(sc, 3, 3.0f);
  int e = blockIdx.x * 256 + threadIdx.x;  // < 8192*16
  int i = e >> 4, j = e & 15;
  float acc = 0.0f;
  for (int n = 0; n < DH; ++n) {
    float q = rintf(hf[(size_t)i * DH + n] / sh);
    q = fminf(fmaxf(q, -3.0f), 3.0f);
    acc = fmaf(q, Woq[n * DOUT + j], acc);
  }
  RT[(size_t)j * NN + i] = (_Float16)acc;
}

// GEMM2: out_int = Aq @ R.  A from bitmask (unpack->f16), BM=128, BN=16, 4 waves (4x1), KSPLIT=8.
__global__ __launch_bounds__(256) void k_gemm2(const unsigned* __restrict__ bits,
                                               const _Float16* __restrict__ RT,
                                               float* __restrict__ P2) {
  __shared__ __align__(16) char As[128 * 128];
  __shared__ __align__(16) char Bs[16 * 128];
  const int t = threadIdx.x;
  const int lane = t & 63;
  const int warp = t >> 6;  // wm = warp
  const int row0 = blockIdx.x * 128;
  const int split = blockIdx.y;
  const int k0base = split * (NN / 8);

  f32x4 acc[2] = {};

  const int ar = t >> 1, ah = t & 1;
  const unsigned* abits = bits + (size_t)(row0 + ar) * (NN / 32) + ah;
  const int arow_sw = (ar & 7) << 4;

  const int bn = t >> 4, bp = t & 15;
  const _Float16* brow = RT + (size_t)bn * NN + bp * 4;
  const int bn_sw = (bn & 7) << 4;

  const int l15 = lane & 15;
  const int koff = (((lane >> 4) << 4)) ^ ((lane & 7) << 4);

  for (int it = 0; it < (NN / 8) / 64; ++it) {
    const int k0 = k0base + it * 64;
    __syncthreads();
    {  // stage A from bits
      unsigned bw = abits[(size_t)(k0 >> 5)];
#pragma unroll
      for (int g = 0; g < 4; ++g) {
        unsigned bb = bw >> (8 * g);
        uint4 w;
        w.x = ((bb & 1u)  ? 0x3C00u : 0u) | ((bb & 2u)   ? 0x3C000000u : 0u);
        w.y = ((bb & 4u)  ? 0x3C00u : 0u) | ((bb & 8u)   ? 0x3C000000u : 0u);
        w.z = ((bb & 16u) ? 0x3C00u : 0u) | ((bb & 32u)  ? 0x3C000000u : 0u);
        w.w = ((bb & 64u) ? 0x3C00u : 0u) | ((bb & 128u) ? 0x3C000000u : 0u);
        *(uint4*)(&As[ar * 128 + ((ah * 64 + g * 16) ^ arow_sw)]) = w;
      }
    }
    {  // stage B: 16 rows x 128B, 8B per thread
      uint2 u = *(const uint2*)(brow + k0);
      *(uint2*)(&Bs[bn * 128 + ((bp * 8) ^ bn_sw)]) = u;
    }
    __syncthreads();
#pragma unroll
    for (int kk = 0; kk < 2; ++kk) {
      half8 af[2], bf;
#pragma unroll
      for (int m = 0; m < 2; ++m)
        af[m] = *(const half8*)(&As[(warp * 32 + m * 16 + l15) * 128 + (koff ^ (kk << 6))]);
      bf = *(const half8*)(&Bs[l15 * 128 + (koff ^ (kk << 6))]);
#pragma unroll
      for (int m = 0; m < 2; ++m)
        acc[m] = __builtin_amdgcn_mfma_f32_16x16x32_f16(af[m], bf, acc[m], 0, 0, 0);
    }
  }
  const int r4 = (lane >> 4) * 4;
#pragma unroll
  for (int m = 0; m < 2; ++m) {
#pragma unroll
    for (int i = 0; i < 4; ++i) {
      int rr = row0 + warp * 32 + m * 16 + r4 + i;
      P2[((size_t)split * NN + rr) * DOUT + l15] = acc[m][i];
    }
  }
}

__global__ __launch_bounds__(256) void k_out(const float* __restrict__ P2,
                                             const unsigned* __restrict__ sc,
                                             float* __restrict__ out) {
  float s = getscale(sc, 3, 3.0f) * getscale(sc, 2, 1.0f);  // scale_h * scale_wo
  int e = blockIdx.x * 256 + threadIdx.x;  // < 8192*16
  float sum = 0.0f;
#pragma unroll
  for (int sp = 0; sp < 8; ++sp) sum += P2[(size_t)sp * NN * DOUT + e];
  out[e] = sum * s;
}

extern "C" void kernel_launch(void* const* d_in, const int* in_sizes, int n_in,
                              void* d_out, int out_size, void* d_ws, size_t ws_size,
                              hipStream_t stream) {
  const float* A  = (const float*)d_in[0];
  const float* X  = (const float*)d_in[1];
  const float* Wi = (const float*)d_in[2];
  const float* Wo = (const float*)d_in[3];
  char* ws = (char*)d_ws;
  unsigned* sc   = (unsigned*)(ws + OFF_SC);
  float* Wiq     = (float*)(ws + OFF_WIQ);
  float* Woq     = (float*)(ws + OFF_WOQ);
  _Float16* YT   = (_Float16*)(ws + OFF_YT);
  unsigned* bits = (unsigned*)(ws + OFF_BITS);
  float* P1      = (float*)(ws + OFF_P1);
  float* hf      = (float*)(ws + OFF_HF);
  _Float16* RT   = (_Float16*)(ws + OFF_RT);
  float* P2      = (float*)(ws + OFF_P2);
  float* out     = (float*)d_out;

  k_init<<<1, 64, 0, stream>>>(sc);
  k_scales<<<66, 256, 0, stream>>>(X, Wi, Wo, sc);
  k_quantW<<<1, 256, 0, stream>>>(Wi, Wo, sc, Wiq, Woq);
  k_Y<<<256, 256, 0, stream>>>(X, Wiq, sc, YT);
  k_gemm1<<<dim3(64, 8), 256, 0, stream>>>(A, YT, bits, P1);
  k_h2<<<2048, 256, 0, stream>>>(P1, sc, hf);
  k_R<<<512, 256, 0, stream>>>(hf, Woq, sc, RT);
  k_gemm2<<<dim3(64, 8), 256, 0, stream>>>(bits, RT, P2);
  k_out<<<512, 256, 0, stream>>>(P2, sc, out);
}

// Round 2
// 164.694 us; speedup vs baseline: 1.1083x; 1.1083x over previous
//
#include <hip/hip_runtime.h>

#define NN 8192
#define DIN 128
#define DH 64
#define DOUT 16
#define KS 16            // K-split for both big GEMMs

typedef _Float16 half8 __attribute__((ext_vector_type(8)));
typedef float f32x4 __attribute__((ext_vector_type(4)));

// workspace layout (bytes); ws_size ~1GB per harness poison-fill evidence
#define OFF_SC   0u          // 4 x u32 scalar max-abs slots (X, Wi, Wo, H)
#define OFF_WIQ  256u        // Wi_int as f32 [128][64]    (32 KB)
#define OFF_WOQ  33280u      // Wo_int as f32 [64][16]     (4 KB)
#define OFF_YT   65536u      // Y^T f16 [64][8192]         (1 MB)  Y = Xq_int @ Wi_int, |Y|<=384
#define OFF_BITS 1114112u    // A>0 bitmask u8 [8192][1024] (8 MB)
#define OFF_P1   9502720u    // h_int partials f32 [16][8192][64] (32 MB)
#define OFF_HF   43057152u   // h (dequant-scaled) f32 [8192][64] (2 MB)
#define OFF_RT   45154304u   // R^T f16 [16][8192] (256 KB) R = hq_int @ Wo_int, |R|<=192
#define OFF_P2   45416448u   // out_int partials f32 [16][8192][16] (8 MB)

__device__ __forceinline__ float getscale(const unsigned* sc, int idx, float qmax) {
  float s = __uint_as_float(sc[idx]) / qmax;
  return (s == 0.0f) ? 1.0f : s;   // matches reference: where(scale==0, 1, scale)
}

__device__ __forceinline__ uint4 expand8(unsigned bb) {  // 8 bits -> 8 f16 {0,1}
  uint4 w;
  w.x = ((bb & 1u)  ? 0x3C00u : 0u) | ((bb & 2u)   ? 0x3C000000u : 0u);
  w.y = ((bb & 4u)  ? 0x3C00u : 0u) | ((bb & 8u)   ? 0x3C000000u : 0u);
  w.z = ((bb & 16u) ? 0x3C00u : 0u) | ((bb & 32u)  ? 0x3C000000u : 0u);
  w.w = ((bb & 64u) ? 0x3C00u : 0u) | ((bb & 128u) ? 0x3C000000u : 0u);
  return w;
}

__global__ void k_init(unsigned* sc) {
  int t = threadIdx.x;
  if (t < 4) sc[t] = 0u;
}

__global__ __launch_bounds__(256) void k_scales(const float* __restrict__ X,
                                                const float* __restrict__ Wi,
                                                const float* __restrict__ Wo,
                                                unsigned* sc) {
  __shared__ float red[256];
  int t = threadIdx.x, b = blockIdx.x;
  float m = 0.0f;
  int slot;
  if (b < 240) {
    slot = 0;
    for (int i = b * 256 + t; i < NN * DIN; i += 240 * 256) m = fmaxf(m, fabsf(X[i]));
  } else if (b == 240) {
    slot = 1;
    for (int i = t; i < DIN * DH; i += 256) m = fmaxf(m, fabsf(Wi[i]));
  } else {
    slot = 2;
    for (int i = t; i < DH * DOUT; i += 256) m = fmaxf(m, fabsf(Wo[i]));
  }
  red[t] = m; __syncthreads();
  for (int s = 128; s > 0; s >>= 1) {
    if (t < s) red[t] = fmaxf(red[t], red[t + s]);
    __syncthreads();
  }
  if (t == 0) atomicMax(&sc[slot], __float_as_uint(red[0]));  // vals >= 0: uint cmp == float cmp
}

__global__ void k_quantW(const float* __restrict__ Wi, const float* __restrict__ Wo,
                         const unsigned* __restrict__ sc,
                         float* __restrict__ Wiq, float* __restrict__ Woq) {
  float swi = getscale(sc, 1, 1.0f);   // W_BIT=2 -> qmax=1
  float swo = getscale(sc, 2, 1.0f);
  int t = threadIdx.x;
  for (int i = t; i < DIN * DH; i += 256) {
    float q = rintf(Wi[i] / swi);                 // rintf == RNE == jnp.round
    Wiq[i] = fminf(fmaxf(q, -1.0f), 1.0f);
  }
  for (int i = t; i < DH * DOUT; i += 256) {
    float q = rintf(Wo[i] / swo);
    Woq[i] = fminf(fmaxf(q, -1.0f), 1.0f);
  }
}

// Y^T[j][k] = sum_n Xq_int[k][n] * Wi_int[n][j]   (exact small integers, |Y|<=384)
__global__ __launch_bounds__(256) void k_Y(const float* __restrict__ X,
                                           const float* __restrict__ Wiq,
                                           const unsigned* __restrict__ sc,
                                           _Float16* __restrict__ YT) {
  __shared__ float Xs[32][DIN];
  __shared__ float Ws[DIN][DH];
  float sx = getscale(sc, 0, 3.0f);   // ACT_BIT=3 -> qmax=3
  int t = threadIdx.x;
  int k0 = blockIdx.x * 32;
  for (int i = t; i < 32 * DIN; i += 256) {
    int r = i >> 7, c = i & 127;
    float q = rintf(X[(size_t)(k0 + r) * DIN + c] / sx);
    Xs[r][c] = fminf(fmaxf(q, -3.0f), 3.0f);
  }
  for (int i = t; i < DIN * DH; i += 256) Ws[i >> 6][i & 63] = Wiq[i];
  __syncthreads();
  int r = t >> 3, j0 = (t & 7) * 8;
  float acc[8] = {0, 0, 0, 0, 0, 0, 0, 0};
  for (int n = 0; n < DIN; ++n) {
    float xv = Xs[r][n];
#pragma unroll
    for (int jj = 0; jj < 8; ++jj) acc[jj] = fmaf(xv, Ws[n][j0 + jj], acc[jj]);
  }
  int k = k0 + r;
#pragma unroll
  for (int jj = 0; jj < 8; ++jj) YT[(size_t)(j0 + jj) * NN + k] = (_Float16)acc[jj];  // exact in f16
}

// GEMM1: h_int = Aq @ Y.  Reads A f32 ONCE (binarize fused), emits bitmask for gemm2.
// BM=32, BN=64, BK=64, 4 waves (2x2), KSPLIT=16. f16 MFMA, exact integer accumulate.
__global__ __launch_bounds__(256) void k_gemm1(const float* __restrict__ A,
                                               const _Float16* __restrict__ YT,
                                               unsigned char* __restrict__ bits,
                                               float* __restrict__ P1) {
  __shared__ __align__(16) char As[32 * 128];  // f16 [32 rows][64 k], XOR-16 swizzled
  __shared__ __align__(16) char Bs[64 * 128];  // f16 [64 n-rows][64 k], same swizzle
  const int t = threadIdx.x;
  const int lane = t & 63;
  const int warp = t >> 6;
  const int wm = warp >> 1, wn = warp & 1;
  const int row0 = blockIdx.x * 32;
  const int split = blockIdx.y;
  const int k0base = split * (NN / KS);   // 512

  f32x4 acc[2] = {};

  const int ar = t >> 3, ak = t & 7;      // A staging: row (0..31), 8-float group (0..7)
  const float* aptr = A + (size_t)(row0 + ar) * NN + ak * 8;
  unsigned char* bptr = bits + (size_t)(row0 + ar) * (NN / 8) + ak;
  const int a_col = (ak * 16) ^ ((ar & 7) << 4);

  const int bn = t >> 2, bp = t & 3;      // B staging: n-row (0..63), 32B quarter
  const _Float16* brow = YT + (size_t)bn * NN + bp * 16;
  const int b_sw = (bn & 7) << 4;

  const int l15 = lane & 15;
  const int koff = ((lane >> 4) << 4) ^ ((l15 & 7) << 4);

  for (int it = 0; it < (NN / KS) / 64; ++it) {   // 8 iterations
    const int k0 = k0base + it * 64;
    __syncthreads();
    {  // stage A: 8 f32 -> binarize -> 8 f16 {0,1} + 1 byte of bitmask
      const float4* p = (const float4*)(aptr + k0);
      float4 v0 = p[0], v1 = p[1];
      unsigned bw = (unsigned)(v0.x > 0.0f)        | ((unsigned)(v0.y > 0.0f) << 1) |
                    ((unsigned)(v0.z > 0.0f) << 2) | ((unsigned)(v0.w > 0.0f) << 3) |
                    ((unsigned)(v1.x > 0.0f) << 4) | ((unsigned)(v1.y > 0.0f) << 5) |
                    ((unsigned)(v1.z > 0.0f) << 6) | ((unsigned)(v1.w > 0.0f) << 7);
      *(uint4*)(&As[ar * 128 + a_col]) = expand8(bw);
      bptr[k0 >> 3] = (unsigned char)bw;
    }
    {  // stage B (Y^T rows are already [n][k])
      const uint4* p = (const uint4*)(brow + k0);
      uint4 u0 = p[0], u1 = p[1];
      *(uint4*)(&Bs[bn * 128 + ((bp * 32) ^ b_sw)]) = u0;
      *(uint4*)(&Bs[bn * 128 + ((bp * 32 + 16) ^ b_sw)]) = u1;
    }
    __syncthreads();
#pragma unroll
    for (int kk = 0; kk < 2; ++kk) {
      half8 af = *(const half8*)(&As[(wm * 16 + l15) * 128 + (koff ^ (kk << 6))]);
#pragma unroll
      for (int n = 0; n < 2; ++n) {
        half8 bf = *(const half8*)(&Bs[(wn * 32 + n * 16 + l15) * 128 + (koff ^ (kk << 6))]);
        acc[n] = __builtin_amdgcn_mfma_f32_16x16x32_f16(af, bf, acc[n], 0, 0, 0);
      }
    }
  }
  const int r4 = (lane >> 4) * 4;
#pragma unroll
  for (int n = 0; n < 2; ++n) {
#pragma unroll
    for (int i = 0; i < 4; ++i) {
      int rr = row0 + wm * 16 + r4 + i;
      int cc = wn * 32 + n * 16 + l15;
      P1[((size_t)split * NN + rr) * DH + cc] = acc[n][i];
    }
  }
}

// reduce K-split partials -> h (scaled), global max|h|
__global__ __launch_bounds__(256) void k_h2(const float* __restrict__ P1,
                                            unsigned* sc, float* __restrict__ hf) {
  float sxw = getscale(sc, 0, 3.0f) * getscale(sc, 1, 1.0f);
  int e = blockIdx.x * 256 + threadIdx.x;  // < 8192*64
  float s = 0.0f;
#pragma unroll
  for (int sp = 0; sp < KS; ++sp) s += P1[(size_t)sp * NN * DH + e];  // exact integer adds
  float v = s * sxw;
  hf[e] = v;
  __shared__ float red[256];
  red[threadIdx.x] = fabsf(v); __syncthreads();
  for (int st = 128; st > 0; st >>= 1) {
    if (threadIdx.x < st) red[threadIdx.x] = fmaxf(red[threadIdx.x], red[threadIdx.x + st]);
    __syncthreads();
  }
  if (threadIdx.x == 0) atomicMax(&sc[3], __float_as_uint(red[0]));
}

// R^T[j][i] = sum_n hq_int[i][n] * Wo_int[n][j]   (|R|<=192, exact in f16)
__global__ __launch_bounds__(256) void k_R(const float* __restrict__ hf,
                                           const float* __restrict__ Woq,
                                           const unsigned* __restrict__ sc,
                                           _Float16* __restrict__ RT) {
  float sh = getscale(sc, 3, 3.0f);
  int e = blockIdx.x * 256 + threadIdx.x;  // < 8192*16
  int i = e >> 4, j = e & 15;
  float acc = 0.0f;
  for (int n = 0; n < DH; ++n) {
    float q = rintf(hf[(size_t)i * DH + n] / sh);
    q = fminf(fmaxf(q, -3.0f), 3.0f);
    acc = fmaf(q, Woq[n * DOUT + j], acc);
  }
  RT[(size_t)j * NN + i] = (_Float16)acc;
}

// GEMM2: out_int = Aq @ R.  A from bitmask (unpack->f16), BM=64, BN=16, BK=64,
// 4 waves (4x1), KSPLIT=16.
__global__ __launch_bounds__(256) void k_gemm2(const unsigned char* __restrict__ bits,
                                               const _Float16* __restrict__ RT,
                                               float* __restrict__ P2) {
  __shared__ __align__(16) char As[64 * 128];
  __shared__ __align__(16) char Bs[16 * 128];
  const int t = threadIdx.x;
  const int lane = t & 63;
  const int warp = t >> 6;  // m-tile index
  const int row0 = blockIdx.x * 64;
  const int split = blockIdx.y;
  const int k0base = split * (NN / KS);

  f32x4 acc = {};

  const int ar = t >> 2, ak = t & 3;    // row (0..63), 16-k group (0..3)
  const unsigned char* bptr = bits + (size_t)(row0 + ar) * (NN / 8) + ak * 2;
  const int a_sw = (ar & 7) << 4;

  const int bn = t >> 4, bp = t & 15;   // n-row (0..15), 8B slot
  const _Float16* brow = RT + (size_t)bn * NN + bp * 4;
  const int b_sw = (bn & 7) << 4;

  const int l15 = lane & 15;
  const int koff = ((lane >> 4) << 4) ^ ((l15 & 7) << 4);

  for (int it = 0; it < (NN / KS) / 64; ++it) {
    const int k0 = k0base + it * 64;
    __syncthreads();
    {  // stage A from bits: 16 bits -> 16 f16
      unsigned bw = *(const unsigned short*)(bptr + (k0 >> 3));
      *(uint4*)(&As[ar * 128 + ((ak * 32) ^ a_sw)])      = expand8(bw & 0xffu);
      *(uint4*)(&As[ar * 128 + ((ak * 32 + 16) ^ a_sw)]) = expand8(bw >> 8);
    }
    {  // stage B: 16 rows x 128B, 8B per thread
      uint2 u = *(const uint2*)(brow + k0);
      *(uint2*)(&Bs[bn * 128 + ((bp * 8) ^ b_sw)]) = u;
    }
    __syncthreads();
#pragma unroll
    for (int kk = 0; kk < 2; ++kk) {
      half8 af = *(const half8*)(&As[(warp * 16 + l15) * 128 + (koff ^ (kk << 6))]);
      half8 bf = *(const half8*)(&Bs[l15 * 128 + (koff ^ (kk << 6))]);
      acc = __builtin_amdgcn_mfma_f32_16x16x32_f16(af, bf, acc, 0, 0, 0);
    }
  }
  const int r4 = (lane >> 4) * 4;
#pragma unroll
  for (int i = 0; i < 4; ++i) {
    int rr = row0 + warp * 16 + r4 + i;
    P2[((size_t)split * NN + rr) * DOUT + l15] = acc[i];
  }
}

__global__ __launch_bounds__(256) void k_out(const float* __restrict__ P2,
                                             const unsigned* __restrict__ sc,
                                             float* __restrict__ out) {
  float s = getscale(sc, 3, 3.0f) * getscale(sc, 2, 1.0f);  // scale_h * scale_wo
  int e = blockIdx.x * 256 + threadIdx.x;  // < 8192*16
  float sum = 0.0f;
#pragma unroll
  for (int sp = 0; sp < KS; ++sp) sum += P2[(size_t)sp * NN * DOUT + e];
  out[e] = sum * s;
}

extern "C" void kernel_launch(void* const* d_in, const int* in_sizes, int n_in,
                              void* d_out, int out_size, void* d_ws, size_t ws_size,
                              hipStream_t stream) {
  const float* A  = (const float*)d_in[0];
  const float* X  = (const float*)d_in[1];
  const float* Wi = (const float*)d_in[2];
  const float* Wo = (const float*)d_in[3];
  char* ws = (char*)d_ws;
  unsigned* sc        = (unsigned*)(ws + OFF_SC);
  float* Wiq          = (float*)(ws + OFF_WIQ);
  float* Woq          = (float*)(ws + OFF_WOQ);
  _Float16* YT        = (_Float16*)(ws + OFF_YT);
  unsigned char* bits = (unsigned char*)(ws + OFF_BITS);
  float* P1           = (float*)(ws + OFF_P1);
  float* hf           = (float*)(ws + OFF_HF);
  _Float16* RT        = (_Float16*)(ws + OFF_RT);
  float* P2           = (float*)(ws + OFF_P2);
  float* out          = (float*)d_out;

  k_init<<<1, 64, 0, stream>>>(sc);
  k_scales<<<242, 256, 0, stream>>>(X, Wi, Wo, sc);
  k_quantW<<<1, 256, 0, stream>>>(Wi, Wo, sc, Wiq, Woq);
  k_Y<<<256, 256, 0, stream>>>(X, Wiq, sc, YT);
  k_gemm1<<<dim3(NN / 32, KS), 256, 0, stream>>>(A, YT, bits, P1);
  k_h2<<<NN * DH / 256, 256, 0, stream>>>(P1, sc, hf);
  k_R<<<NN * DOUT / 256, 256, 0, stream>>>(hf, Woq, sc, RT);
  k_gemm2<<<dim3(NN / 64, KS), 256, 0, stream>>>(bits, RT, P2);
  k_out<<<NN * DOUT / 256, 256, 0, stream>>>(P2, sc, out);
}

// Round 4
// 147.215 us; speedup vs baseline: 1.2398x; 1.1187x over previous
//
#include <hip/hip_runtime.h>

#define NN 8192
#define DIN 128
#define DH 64
#define DOUT 16
#define KS 16

typedef _Float16 half8 __attribute__((ext_vector_type(8)));
typedef float f32x4 __attribute__((ext_vector_type(4)));

// workspace layout (bytes); ws ~1GB per harness fill evidence
#define OFF_SC    0u         // sc[4]: maxX, maxWi, maxWo, maxH (raw f32 bits)
#define OFF_PART  256u       // part[256]: per-block partial maxes (f32 bits)
#define OFF_WIQ   2048u      // f32 [128][64]
#define OFF_WOQ   34816u     // f32 [64][16]
#define OFF_YT    65536u     // f16 [64][8192]   (1 MB)   Y = Xq_int @ Wi_int, |Y|<=384
#define OFF_RT    1114112u   // f16 [16][8192]   (256 KB) R = hq_int @ Wo_int, |R|<=192
#define OFF_HF    1376256u   // f32 [8192][64]   (2 MB)
#define OFF_BITS  3473408u   // u8  [8192][1024] (8 MB)   A>0 bitmask
#define OFF_P1    11862016u  // f32 [16][8192][64] (32 MB)
#define OFF_P2    45416448u  // f32 [16][8192][16] (8 MB)

__device__ __forceinline__ float getscale(const unsigned* sc, int idx, float qmax) {
  float s = __uint_as_float(sc[idx]) / qmax;
  return (s == 0.0f) ? 1.0f : s;   // matches reference where(scale==0,1,scale)
}

__device__ __forceinline__ half8 expand8(unsigned bb) {  // 8 bits -> 8 f16 {0,1}
  uint4 w;
  w.x = ((bb & 1u)  ? 0x3C00u : 0u) | ((bb & 2u)   ? 0x3C000000u : 0u);
  w.y = ((bb & 4u)  ? 0x3C00u : 0u) | ((bb & 8u)   ? 0x3C000000u : 0u);
  w.z = ((bb & 16u) ? 0x3C00u : 0u) | ((bb & 32u)  ? 0x3C000000u : 0u);
  w.w = ((bb & 64u) ? 0x3C00u : 0u) | ((bb & 128u) ? 0x3C000000u : 0u);
  return __builtin_bit_cast(half8, w);
}

// partial maxes, no atomics, no init needed (every slot written unconditionally)
__global__ __launch_bounds__(256) void k_scales(const float* __restrict__ X,
                                                const float* __restrict__ Wi,
                                                const float* __restrict__ Wo,
                                                unsigned* part) {
  __shared__ float red[256];
  int t = threadIdx.x, b = blockIdx.x;
  float m = 0.0f;
  if (b < 240) {
    for (int i = b * 256 + t; i < NN * DIN; i += 240 * 256) m = fmaxf(m, fabsf(X[i]));
  } else if (b == 240) {
    for (int i = t; i < DIN * DH; i += 256) m = fmaxf(m, fabsf(Wi[i]));
  } else {
    for (int i = t; i < DH * DOUT; i += 256) m = fmaxf(m, fabsf(Wo[i]));
  }
  red[t] = m; __syncthreads();
  for (int s = 128; s > 0; s >>= 1) {
    if (t < s) red[t] = fmaxf(red[t], red[t + s]);
    __syncthreads();
  }
  if (t == 0) part[b] = __float_as_uint(red[0]);
}

// reduce partials -> sc, quantize weights, zero the h-max slot
__global__ __launch_bounds__(256) void k_quantW(const float* __restrict__ Wi,
                                                const float* __restrict__ Wo,
                                                const unsigned* __restrict__ part,
                                                unsigned* sc,
                                                float* __restrict__ Wiq,
                                                float* __restrict__ Woq) {
  __shared__ float red[256];
  int t = threadIdx.x;
  red[t] = (t < 240) ? __uint_as_float(part[t]) : 0.0f;
  __syncthreads();
  for (int s = 128; s > 0; s >>= 1) {
    if (t < s) red[t] = fmaxf(red[t], red[t + s]);
    __syncthreads();
  }
  if (t == 0) {
    sc[0] = __float_as_uint(red[0]);
    sc[1] = part[240];
    sc[2] = part[241];
    sc[3] = 0u;
  }
  float swi = __uint_as_float(part[240]); swi = (swi == 0.0f) ? 1.0f : swi;  // qmax=1
  float swo = __uint_as_float(part[241]); swo = (swo == 0.0f) ? 1.0f : swo;
  for (int i = t; i < DIN * DH; i += 256) {
    float q = rintf(Wi[i] / swi);
    Wiq[i] = fminf(fmaxf(q, -1.0f), 1.0f);
  }
  for (int i = t; i < DH * DOUT; i += 256) {
    float q = rintf(Wo[i] / swo);
    Woq[i] = fminf(fmaxf(q, -1.0f), 1.0f);
  }
}

// fused: blocks [0,4096): linear-stream A -> bits; blocks [4096,5120): Y^T = (Xq @ Wiq)^T
__global__ __launch_bounds__(256) void k_bitsY(const float* __restrict__ A,
                                               const float* __restrict__ X,
                                               const float* __restrict__ Wiq,
                                               const unsigned* __restrict__ sc,
                                               unsigned char* __restrict__ bits,
                                               _Float16* __restrict__ YT) {
  __shared__ float Xs[8][129];   // +1 pad: breaks 8-way bank conflict on Xs[r][n]
  __shared__ float Ws[DIN][DH];
  const int t = threadIdx.x, bx = blockIdx.x;
  if (bx < 4096) {
    // ---- bits path: perfectly linear read of A (64 floats/thread), linear 8B bit writes
    const int g = bx * 256 + t;                       // 1M threads cover 64M floats
    const float4* ap = (const float4*)(A + (size_t)g * 64);
    float4 v[16];
#pragma unroll
    for (int u = 0; u < 16; ++u) v[u] = ap[u];
    unsigned lo = 0u, hi = 0u;
#pragma unroll
    for (int u = 0; u < 8; ++u) {
      lo |= ((unsigned)(v[u].x > 0.0f) << (4 * u + 0)) | ((unsigned)(v[u].y > 0.0f) << (4 * u + 1)) |
            ((unsigned)(v[u].z > 0.0f) << (4 * u + 2)) | ((unsigned)(v[u].w > 0.0f) << (4 * u + 3));
      float4 w = v[u + 8];
      hi |= ((unsigned)(w.x > 0.0f) << (4 * u + 0)) | ((unsigned)(w.y > 0.0f) << (4 * u + 1)) |
            ((unsigned)(w.z > 0.0f) << (4 * u + 2)) | ((unsigned)(w.w > 0.0f) << (4 * u + 3));
    }
    uint2 bw; bw.x = lo; bw.y = hi;
    *(uint2*)(bits + (size_t)g * 8) = bw;
    return;
  }
  // ---- Y path
  float sx = getscale(sc, 0, 3.0f);
  const int by = bx - 4096;          // 0..1023, 8 k-rows each
  const int k0 = by * 8;
  for (int i = t; i < 8 * DIN; i += 256) {
    int r = i >> 7, c = i & 127;
    float q = rintf(X[(size_t)(k0 + r) * DIN + c] / sx);
    Xs[r][c] = fminf(fmaxf(q, -3.0f), 3.0f);
  }
  for (int i = t; i < DIN * DH; i += 256) Ws[i >> 6][i & 63] = Wiq[i];
  __syncthreads();
  const int r = t & 7, jp = t >> 3, j = jp * 2;
  float a0 = 0.0f, a1 = 0.0f;
  for (int n = 0; n < DIN; ++n) {
    float xv = Xs[r][n];
    a0 = fmaf(xv, Ws[n][j], a0);
    a1 = fmaf(xv, Ws[n][j + 1], a1);
  }
  YT[(size_t)j * NN + k0 + r]       = (_Float16)a0;   // exact integers in f16
  YT[(size_t)(j + 1) * NN + k0 + r] = (_Float16)a1;
}

// GEMM1: h_int = Aq @ Y. A expanded from bits IN REGISTERS (1 byte = 1 MFMA A-frag).
// BM=64, BN=64, BK=64, 4 waves (2x2), KSPLIT=16, B LDS-staged with reg-prefetch.
__global__ __launch_bounds__(256) void k_gemm1(const unsigned char* __restrict__ bits,
                                               const _Float16* __restrict__ YT,
                                               float* __restrict__ P1) {
  __shared__ __align__(16) char Bs[64 * 128];   // f16 [64 n][64 k], XOR-16 swizzled
  const int t = threadIdx.x, lane = t & 63, warp = t >> 6;
  const int wm = warp >> 1, wn = warp & 1;
  const int row0 = blockIdx.x * 64;
  const int split = blockIdx.y;
  const int l15 = lane & 15, lq = lane >> 4;
  const int sh8 = lq * 8;

  f32x4 acc[2][2] = {};

  const int bn = t >> 2, bp = t & 3;
  const _Float16* bsrc = YT + (size_t)bn * NN + split * 512 + bp * 16;
  char* bdst0 = &Bs[bn * 128 + ((bp * 32) ^ ((bn & 7) << 4))];
  char* bdst1 = &Bs[bn * 128 + ((bp * 32 + 16) ^ ((bn & 7) << 4))];

  const unsigned char* brow0 = bits + (size_t)(row0 + wm * 32 + l15) * 1024 + split * 64;
  const unsigned char* brow1 = brow0 + 16 * 1024;

  uint4 breg0 = *(const uint4*)(bsrc);
  uint4 breg1 = *(const uint4*)(bsrc + 8);

  for (int it = 0; it < 8; ++it) {
    __syncthreads();
    *(uint4*)bdst0 = breg0;
    *(uint4*)bdst1 = breg1;
    if (it < 7) {  // prefetch next B tile (BK=64 f16 elements per iteration!)
      breg0 = *(const uint4*)(bsrc + (it + 1) * 64);
      breg1 = *(const uint4*)(bsrc + (it + 1) * 64 + 8);
    }
    uint2 w0 = *(const uint2*)(brow0 + it * 8);   // 64 A-bits for this wave's rows
    uint2 w1 = *(const uint2*)(brow1 + it * 8);
    __syncthreads();
#pragma unroll
    for (int kk = 0; kk < 2; ++kk) {
      half8 af0 = expand8(((kk ? w0.y : w0.x) >> sh8) & 0xffu);
      half8 af1 = expand8(((kk ? w1.y : w1.x) >> sh8) & 0xffu);
#pragma unroll
      for (int n = 0; n < 2; ++n) {
        half8 bf = *(const half8*)(&Bs[(wn * 32 + n * 16 + l15) * 128 +
                                       ((lq * 16 + kk * 64) ^ ((l15 & 7) << 4))]);
        acc[0][n] = __builtin_amdgcn_mfma_f32_16x16x32_f16(af0, bf, acc[0][n], 0, 0, 0);
        acc[1][n] = __builtin_amdgcn_mfma_f32_16x16x32_f16(af1, bf, acc[1][n], 0, 0, 0);
      }
    }
  }
  const int r4 = lq * 4;
#pragma unroll
  for (int mf = 0; mf < 2; ++mf) {
#pragma unroll
    for (int n = 0; n < 2; ++n) {
#pragma unroll
      for (int i = 0; i < 4; ++i) {
        int rr = row0 + wm * 32 + mf * 16 + r4 + i;
        int cc = wn * 32 + n * 16 + l15;
        P1[((size_t)split * NN + rr) * DH + cc] = acc[mf][n][i];
      }
    }
  }
}

// reduce K-split partials -> h (scaled), per-block max -> atomicMax (512 atomics)
__global__ __launch_bounds__(256) void k_h2(const float* __restrict__ P1,
                                            unsigned* sc, float* __restrict__ hf) {
  float sxw = getscale(sc, 0, 3.0f) * getscale(sc, 1, 1.0f);
  int idx = blockIdx.x * 256 + threadIdx.x;          // float4 index < 131072
  const float4* p = (const float4*)P1;
  float4 s = {0, 0, 0, 0};
#pragma unroll
  for (int sp = 0; sp < KS; ++sp) {
    float4 v = p[(size_t)sp * (NN * DH / 4) + idx];  // exact integer adds
    s.x += v.x; s.y += v.y; s.z += v.z; s.w += v.w;
  }
  s.x *= sxw; s.y *= sxw; s.z *= sxw; s.w *= sxw;
  ((float4*)hf)[idx] = s;
  float m = fmaxf(fmaxf(fabsf(s.x), fabsf(s.y)), fmaxf(fabsf(s.z), fabsf(s.w)));
  __shared__ float red[256];
  red[threadIdx.x] = m; __syncthreads();
  for (int st = 128; st > 0; st >>= 1) {
    if (threadIdx.x < st) red[threadIdx.x] = fmaxf(red[threadIdx.x], red[threadIdx.x + st]);
    __syncthreads();
  }
  if (threadIdx.x == 0) atomicMax(&sc[3], __float_as_uint(red[0]));
}

// R^T[j][i] = sum_n hq_int[i][n] * Wo_int[n][j]   (|R|<=192, exact in f16)
__global__ __launch_bounds__(256) void k_R(const float* __restrict__ hf,
                                           const float* __restrict__ Woq,
                                           const unsigned* __restrict__ sc,
                                           _Float16* __restrict__ RT) {
  __shared__ float WoS[DH][DOUT];
  float sh = getscale(sc, 3, 3.0f);
  int t = threadIdx.x;
  for (int i = t; i < DH * DOUT; i += 256) WoS[i >> 4][i & 15] = Woq[i];
  __syncthreads();
  int i = blockIdx.x * 16 + (t & 15), j = t >> 4;
  const float4* hp = (const float4*)(hf + (size_t)i * DH);
  float acc = 0.0f;
#pragma unroll 4
  for (int nb = 0; nb < 16; ++nb) {
    float4 h4 = hp[nb];
    float q;
    q = fminf(fmaxf(rintf(h4.x / sh), -3.0f), 3.0f); acc = fmaf(q, WoS[nb * 4 + 0][j], acc);
    q = fminf(fmaxf(rintf(h4.y / sh), -3.0f), 3.0f); acc = fmaf(q, WoS[nb * 4 + 1][j], acc);
    q = fminf(fmaxf(rintf(h4.z / sh), -3.0f), 3.0f); acc = fmaf(q, WoS[nb * 4 + 2][j], acc);
    q = fminf(fmaxf(rintf(h4.w / sh), -3.0f), 3.0f); acc = fmaf(q, WoS[nb * 4 + 3][j], acc);
  }
  RT[(size_t)j * NN + i] = (_Float16)acc;
}

// GEMM2: out_int = Aq @ R. A from bits in regs; R^T slice LDS-staged ONCE per block.
// BM=64, BN=16, 4 waves (m-split), KSPLIT=16, 8 iters, one barrier total.
__global__ __launch_bounds__(256) void k_gemm2(const unsigned char* __restrict__ bits,
                                               const _Float16* __restrict__ RT,
                                               float* __restrict__ P2) {
  __shared__ __align__(16) char Rs[16 * 1024];   // f16 [16 n][512 k], XOR-16 swizzled
  const int t = threadIdx.x, lane = t & 63, warp = t >> 6;
  const int row0 = blockIdx.x * 64;
  const int split = blockIdx.y;
  const int l15 = lane & 15, lq = lane >> 4;
  const int sh8 = lq * 8;

  {  // stage R^T[16][512] slice once
    const int rr = t >> 4, cb = (t & 15) * 64;    // row, 64-byte chunk
    const uint4* src = (const uint4*)(RT + (size_t)rr * NN + split * 512 + (t & 15) * 32);
    char* base = &Rs[rr * 1024];
    const int sw = (rr & 7) << 4;
#pragma unroll
    for (int u = 0; u < 4; ++u) *(uint4*)(&base[(cb + u * 16) ^ sw]) = src[u];
  }
  __syncthreads();

  const unsigned char* brow = bits + (size_t)(row0 + warp * 16 + l15) * 1024 + split * 64;
  f32x4 acc = {};
  const int rsw = (l15 & 7) << 4;
#pragma unroll
  for (int it = 0; it < 8; ++it) {
    uint2 w = *(const uint2*)(brow + it * 8);
#pragma unroll
    for (int kk = 0; kk < 2; ++kk) {
      half8 af = expand8(((kk ? w.y : w.x) >> sh8) & 0xffu);
      half8 bf = *(const half8*)(&Rs[l15 * 1024 + ((it * 128 + lq * 16 + kk * 64) ^ rsw)]);
      acc = __builtin_amdgcn_mfma_f32_16x16x32_f16(af, bf, acc, 0, 0, 0);
    }
  }
  const int r4 = lq * 4;
#pragma unroll
  for (int i = 0; i < 4; ++i) {
    int rr = row0 + warp * 16 + r4 + i;
    P2[((size_t)split * NN + rr) * DOUT + l15] = acc[i];
  }
}

__global__ __launch_bounds__(256) void k_out(const float* __restrict__ P2,
                                             const unsigned* __restrict__ sc,
                                             float* __restrict__ out) {
  float s = getscale(sc, 3, 3.0f) * getscale(sc, 2, 1.0f);
  int idx = blockIdx.x * 256 + threadIdx.x;          // float4 index < 32768
  const float4* p = (const float4*)P2;
  float4 acc = {0, 0, 0, 0};
#pragma unroll
  for (int sp = 0; sp < KS; ++sp) {
    float4 v = p[(size_t)sp * (NN * DOUT / 4) + idx];
    acc.x += v.x; acc.y += v.y; acc.z += v.z; acc.w += v.w;
  }
  acc.x *= s; acc.y *= s; acc.z *= s; acc.w *= s;
  ((float4*)out)[idx] = acc;
}

extern "C" void kernel_launch(void* const* d_in, const int* in_sizes, int n_in,
                              void* d_out, int out_size, void* d_ws, size_t ws_size,
                              hipStream_t stream) {
  const float* A  = (const float*)d_in[0];
  const float* X  = (const float*)d_in[1];
  const float* Wi = (const float*)d_in[2];
  const float* Wo = (const float*)d_in[3];
  char* ws = (char*)d_ws;
  unsigned* sc        = (unsigned*)(ws + OFF_SC);
  unsigned* part      = (unsigned*)(ws + OFF_PART);
  float* Wiq          = (float*)(ws + OFF_WIQ);
  float* Woq          = (float*)(ws + OFF_WOQ);
  _Float16* YT        = (_Float16*)(ws + OFF_YT);
  _Float16* RT        = (_Float16*)(ws + OFF_RT);
  float* hf           = (float*)(ws + OFF_HF);
  unsigned char* bits = (unsigned char*)(ws + OFF_BITS);
  float* P1           = (float*)(ws + OFF_P1);
  float* P2           = (float*)(ws + OFF_P2);
  float* out          = (float*)d_out;

  k_scales<<<242, 256, 0, stream>>>(X, Wi, Wo, part);
  k_quantW<<<1, 256, 0, stream>>>(Wi, Wo, part, sc, Wiq, Woq);
  k_bitsY<<<5120, 256, 0, stream>>>(A, X, Wiq, sc, bits, YT);
  k_gemm1<<<dim3(NN / 64, KS), 256, 0, stream>>>(bits, YT, P1);
  k_h2<<<NN * DH / 1024, 256, 0, stream>>>(P1, sc, hf);
  k_R<<<NN / 16, 256, 0, stream>>>(hf, Woq, sc, RT);
  k_gemm2<<<dim3(NN / 64, KS), 256, 0, stream>>>(bits, RT, P2);
  k_out<<<NN * DOUT / 1024, 256, 0, stream>>>(P2, sc, out);
}

// Round 5
// 129.921 us; speedup vs baseline: 1.4049x; 1.1331x over previous
//
#include <hip/hip_runtime.h>

#define NN 8192
#define DIN 128
#define DH 64
#define DOUT 16
#define KS 16

typedef _Float16 half8 __attribute__((ext_vector_type(8)));
typedef float f32x4 __attribute__((ext_vector_type(4)));

// workspace layout (bytes); ws ~1GB per harness fill evidence
#define OFF_SC    0u         // sc[4]: maxX, maxWi, maxWo, maxH (raw f32 bits)
#define OFF_PART  256u       // part[256]: per-block partial maxes (f32 bits)
#define OFF_WIQ   2048u      // f32 [128][64]
#define OFF_WOQ   34816u     // f32 [64][16]
#define OFF_YT    65536u     // f16 [64][8192]   (1 MB)   Y = Xq_int @ Wi_int, |Y|<=384
#define OFF_RT    1114112u   // f16 [16][8192]   (256 KB) R = hq_int @ Wo_int, |R|<=192
#define OFF_HF    1376256u   // f32 [8192][64]   (2 MB)
#define OFF_BITS  3473408u   // u8  [8192][1024] (8 MB)   A>0 bitmask
#define OFF_P1    11862016u  // f32 [16][8192][64] (32 MB)
#define OFF_P2    45416448u  // f32 [16][8192][16] (8 MB)

__device__ __forceinline__ float getscale(const unsigned* sc, int idx, float qmax) {
  float s = __uint_as_float(sc[idx]) / qmax;
  return (s == 0.0f) ? 1.0f : s;   // matches reference where(scale==0,1,scale)
}

__device__ __forceinline__ half8 expand8(unsigned bb) {  // 8 bits -> 8 f16 {0,1}
  uint4 w;
  w.x = ((bb & 1u)  ? 0x3C00u : 0u) | ((bb & 2u)   ? 0x3C000000u : 0u);
  w.y = ((bb & 4u)  ? 0x3C00u : 0u) | ((bb & 8u)   ? 0x3C000000u : 0u);
  w.z = ((bb & 16u) ? 0x3C00u : 0u) | ((bb & 32u)  ? 0x3C000000u : 0u);
  w.w = ((bb & 64u) ? 0x3C00u : 0u) | ((bb & 128u) ? 0x3C000000u : 0u);
  return __builtin_bit_cast(half8, w);
}

// partial maxes, no atomics, no init needed (every slot written unconditionally)
__global__ __launch_bounds__(256) void k_scales(const float* __restrict__ X,
                                                const float* __restrict__ Wi,
                                                const float* __restrict__ Wo,
                                                unsigned* part) {
  __shared__ float red[256];
  int t = threadIdx.x, b = blockIdx.x;
  float m = 0.0f;
  if (b < 240) {
    for (int i = b * 256 + t; i < NN * DIN; i += 240 * 256) m = fmaxf(m, fabsf(X[i]));
  } else if (b == 240) {
    for (int i = t; i < DIN * DH; i += 256) m = fmaxf(m, fabsf(Wi[i]));
  } else {
    for (int i = t; i < DH * DOUT; i += 256) m = fmaxf(m, fabsf(Wo[i]));
  }
  red[t] = m; __syncthreads();
  for (int s = 128; s > 0; s >>= 1) {
    if (t < s) red[t] = fmaxf(red[t], red[t + s]);
    __syncthreads();
  }
  if (t == 0) part[b] = __float_as_uint(red[0]);
}

// reduce partials -> sc, quantize weights, zero the h-max slot
__global__ __launch_bounds__(256) void k_quantW(const float* __restrict__ Wi,
                                                const float* __restrict__ Wo,
                                                const unsigned* __restrict__ part,
                                                unsigned* sc,
                                                float* __restrict__ Wiq,
                                                float* __restrict__ Woq) {
  __shared__ float red[256];
  int t = threadIdx.x;
  red[t] = (t < 240) ? __uint_as_float(part[t]) : 0.0f;
  __syncthreads();
  for (int s = 128; s > 0; s >>= 1) {
    if (t < s) red[t] = fmaxf(red[t], red[t + s]);
    __syncthreads();
  }
  if (t == 0) {
    sc[0] = __float_as_uint(red[0]);
    sc[1] = part[240];
    sc[2] = part[241];
    sc[3] = 0u;
  }
  float swi = __uint_as_float(part[240]); swi = (swi == 0.0f) ? 1.0f : swi;  // qmax=1
  float swo = __uint_as_float(part[241]); swo = (swo == 0.0f) ? 1.0f : swo;
  for (int i = t; i < DIN * DH; i += 256) {
    float q = rintf(Wi[i] / swi);
    Wiq[i] = fminf(fmaxf(q, -1.0f), 1.0f);
  }
  for (int i = t; i < DH * DOUT; i += 256) {
    float q = rintf(Wo[i] / swo);
    Woq[i] = fminf(fmaxf(q, -1.0f), 1.0f);
  }
}

// fused: blocks [0,4096): ballot-binarize A -> bits (lane i reads element i:
// fully coalesced dword loads; __ballot packs 64 bits in element order for free).
// blocks [4096,5120): Y^T = (Xq @ Wiq)^T.
__global__ __launch_bounds__(256) void k_bitsY(const float* __restrict__ A,
                                               const float* __restrict__ X,
                                               const float* __restrict__ Wiq,
                                               const unsigned* __restrict__ sc,
                                               unsigned char* __restrict__ bits,
                                               _Float16* __restrict__ YT) {
  __shared__ float Xs[8][129];
  __shared__ float Ws[DIN][DH];
  const int t = threadIdx.x, bx = blockIdx.x;
  if (bx < 4096) {
    const int lane = t & 63, warp = t >> 6;
    const size_t wbase = ((size_t)bx * 4 + warp) * 4096;   // floats; 4096 per wave
    const float* ap = A + wbase + lane;
    unsigned char* bp = bits + (wbase >> 3);
    const int l8 = lane & 7;
#pragma unroll
    for (int g = 0; g < 8; ++g) {                          // 512 floats per group
      float x0 = ap[g * 512 + 0 * 64];
      float x1 = ap[g * 512 + 1 * 64];
      float x2 = ap[g * 512 + 2 * 64];
      float x3 = ap[g * 512 + 3 * 64];
      float x4 = ap[g * 512 + 4 * 64];
      float x5 = ap[g * 512 + 5 * 64];
      float x6 = ap[g * 512 + 6 * 64];
      float x7 = ap[g * 512 + 7 * 64];
      unsigned long long m0 = __ballot(x0 > 0.0f);
      unsigned long long m1 = __ballot(x1 > 0.0f);
      unsigned long long m2 = __ballot(x2 > 0.0f);
      unsigned long long m3 = __ballot(x3 > 0.0f);
      unsigned long long m4 = __ballot(x4 > 0.0f);
      unsigned long long m5 = __ballot(x5 > 0.0f);
      unsigned long long m6 = __ballot(x6 > 0.0f);
      unsigned long long m7 = __ballot(x7 > 0.0f);
      unsigned long long mine = m0;
      mine = (l8 == 1) ? m1 : mine;
      mine = (l8 == 2) ? m2 : mine;
      mine = (l8 == 3) ? m3 : mine;
      mine = (l8 == 4) ? m4 : mine;
      mine = (l8 == 5) ? m5 : mine;
      mine = (l8 == 6) ? m6 : mine;
      mine = (l8 == 7) ? m7 : mine;
      if (lane < 8) *(unsigned long long*)(bp + g * 64 + l8 * 8) = mine;
    }
    return;
  }
  // ---- Y path
  float sx = getscale(sc, 0, 3.0f);
  const int by = bx - 4096;          // 0..1023, 8 k-rows each
  const int k0 = by * 8;
  for (int i = t; i < 8 * DIN; i += 256) {
    int r = i >> 7, c = i & 127;
    float q = rintf(X[(size_t)(k0 + r) * DIN + c] / sx);
    Xs[r][c] = fminf(fmaxf(q, -3.0f), 3.0f);
  }
  for (int i = t; i < DIN * DH; i += 256) Ws[i >> 6][i & 63] = Wiq[i];
  __syncthreads();
  const int r = t & 7, jp = t >> 3, j = jp * 2;
  float a0 = 0.0f, a1 = 0.0f;
  for (int n = 0; n < DIN; ++n) {
    float xv = Xs[r][n];
    a0 = fmaf(xv, Ws[n][j], a0);
    a1 = fmaf(xv, Ws[n][j + 1], a1);
  }
  YT[(size_t)j * NN + k0 + r]       = (_Float16)a0;   // exact integers in f16
  YT[(size_t)(j + 1) * NN + k0 + r] = (_Float16)a1;
}

// GEMM1: h_int = Aq @ Y. A from bits in regs (1 byte = 1 MFMA A-frag k-slice).
// BM=128, BN=64(full), BK=64, 4 waves m-split, each expand8 feeds 4 MFMAs.
__global__ __launch_bounds__(256) void k_gemm1(const unsigned char* __restrict__ bits,
                                               const _Float16* __restrict__ YT,
                                               float* __restrict__ P1) {
  __shared__ __align__(16) char Bs[64 * 128];   // f16 [64 n][64 k], XOR-16 swizzled
  const int t = threadIdx.x, lane = t & 63, warp = t >> 6;  // warp = m-tile
  const int row0 = blockIdx.x * 128;
  const int split = blockIdx.y;
  const int l15 = lane & 15, lq = lane >> 4;
  const int sh8 = lq * 8;

  f32x4 acc[2][4] = {};

  const int bn = t >> 2, bp = t & 3;
  const _Float16* bsrc = YT + (size_t)bn * NN + split * 512 + bp * 16;
  char* bdst0 = &Bs[bn * 128 + ((bp * 32) ^ ((bn & 7) << 4))];
  char* bdst1 = &Bs[bn * 128 + ((bp * 32 + 16) ^ ((bn & 7) << 4))];

  const unsigned char* brow0 = bits + (size_t)(row0 + warp * 32 + l15) * 1024 + split * 64;
  const unsigned char* brow1 = brow0 + 16 * 1024;

  uint4 breg0 = *(const uint4*)(bsrc);
  uint4 breg1 = *(const uint4*)(bsrc + 8);

  for (int it = 0; it < 8; ++it) {
    __syncthreads();
    *(uint4*)bdst0 = breg0;
    *(uint4*)bdst1 = breg1;
    if (it < 7) {  // prefetch next B tile (BK=64 f16 elements per iteration)
      breg0 = *(const uint4*)(bsrc + (it + 1) * 64);
      breg1 = *(const uint4*)(bsrc + (it + 1) * 64 + 8);
    }
    uint2 w0 = *(const uint2*)(brow0 + it * 8);   // 64 A-bits, rows l15 / l15+16
    uint2 w1 = *(const uint2*)(brow1 + it * 8);
    __syncthreads();
#pragma unroll
    for (int kk = 0; kk < 2; ++kk) {
      half8 af0 = expand8(((kk ? w0.y : w0.x) >> sh8) & 0xffu);
      half8 af1 = expand8(((kk ? w1.y : w1.x) >> sh8) & 0xffu);
#pragma unroll
      for (int n = 0; n < 4; ++n) {
        half8 bf = *(const half8*)(&Bs[(n * 16 + l15) * 128 +
                                       ((lq * 16 + kk * 64) ^ ((l15 & 7) << 4))]);
        acc[0][n] = __builtin_amdgcn_mfma_f32_16x16x32_f16(af0, bf, acc[0][n], 0, 0, 0);
        acc[1][n] = __builtin_amdgcn_mfma_f32_16x16x32_f16(af1, bf, acc[1][n], 0, 0, 0);
      }
    }
  }
  const int r4 = lq * 4;
#pragma unroll
  for (int mf = 0; mf < 2; ++mf) {
#pragma unroll
    for (int n = 0; n < 4; ++n) {
#pragma unroll
      for (int i = 0; i < 4; ++i) {
        int rr = row0 + warp * 32 + mf * 16 + r4 + i;
        int cc = n * 16 + l15;
        P1[((size_t)split * NN + rr) * DH + cc] = acc[mf][n][i];
      }
    }
  }
}

// reduce K-split partials -> h (scaled), per-block max -> atomicMax (512 atomics)
__global__ __launch_bounds__(256) void k_h2(const float* __restrict__ P1,
                                            unsigned* sc, float* __restrict__ hf) {
  float sxw = getscale(sc, 0, 3.0f) * getscale(sc, 1, 1.0f);
  int idx = blockIdx.x * 256 + threadIdx.x;          // float4 index < 131072
  const float4* p = (const float4*)P1;
  float4 s = {0, 0, 0, 0};
#pragma unroll
  for (int sp = 0; sp < KS; ++sp) {
    float4 v = p[(size_t)sp * (NN * DH / 4) + idx];  // exact integer adds
    s.x += v.x; s.y += v.y; s.z += v.z; s.w += v.w;
  }
  s.x *= sxw; s.y *= sxw; s.z *= sxw; s.w *= sxw;
  ((float4*)hf)[idx] = s;
  float m = fmaxf(fmaxf(fabsf(s.x), fabsf(s.y)), fmaxf(fabsf(s.z), fabsf(s.w)));
  __shared__ float red[256];
  red[threadIdx.x] = m; __syncthreads();
  for (int st = 128; st > 0; st >>= 1) {
    if (threadIdx.x < st) red[threadIdx.x] = fmaxf(red[threadIdx.x], red[threadIdx.x + st]);
    __syncthreads();
  }
  if (threadIdx.x == 0) atomicMax(&sc[3], __float_as_uint(red[0]));
}

// R^T[j][i] = sum_n hq_int[i][n] * Wo_int[n][j]   (|R|<=192, exact in f16)
__global__ __launch_bounds__(256) void k_R(const float* __restrict__ hf,
                                           const float* __restrict__ Woq,
                                           const unsigned* __restrict__ sc,
                                           _Float16* __restrict__ RT) {
  __shared__ float WoS[DH][DOUT];
  float sh = getscale(sc, 3, 3.0f);
  int t = threadIdx.x;
  for (int i = t; i < DH * DOUT; i += 256) WoS[i >> 4][i & 15] = Woq[i];
  __syncthreads();
  int i = blockIdx.x * 16 + (t & 15), j = t >> 4;
  const float4* hp = (const float4*)(hf + (size_t)i * DH);
  float acc = 0.0f;
#pragma unroll 4
  for (int nb = 0; nb < 16; ++nb) {
    float4 h4 = hp[nb];
    float q;
    q = fminf(fmaxf(rintf(h4.x / sh), -3.0f), 3.0f); acc = fmaf(q, WoS[nb * 4 + 0][j], acc);
    q = fminf(fmaxf(rintf(h4.y / sh), -3.0f), 3.0f); acc = fmaf(q, WoS[nb * 4 + 1][j], acc);
    q = fminf(fmaxf(rintf(h4.z / sh), -3.0f), 3.0f); acc = fmaf(q, WoS[nb * 4 + 2][j], acc);
    q = fminf(fmaxf(rintf(h4.w / sh), -3.0f), 3.0f); acc = fmaf(q, WoS[nb * 4 + 3][j], acc);
  }
  RT[(size_t)j * NN + i] = (_Float16)acc;
}

// GEMM2: out_int = Aq @ R. A from bits in regs; R^T slice LDS-staged ONCE per block.
// BM=64, BN=16, 4 waves (m-split), KSPLIT=16, 8 iters, one barrier total.
__global__ __launch_bounds__(256) void k_gemm2(const unsigned char* __restrict__ bits,
                                               const _Float16* __restrict__ RT,
                                               float* __restrict__ P2) {
  __shared__ __align__(16) char Rs[16 * 1024];   // f16 [16 n][512 k], XOR-16 swizzled
  const int t = threadIdx.x, lane = t & 63, warp = t >> 6;
  const int row0 = blockIdx.x * 64;
  const int split = blockIdx.y;
  const int l15 = lane & 15, lq = lane >> 4;
  const int sh8 = lq * 8;

  {  // stage R^T[16][512] slice once
    const int rr = t >> 4, cb = (t & 15) * 64;    // row, 64-byte chunk
    const uint4* src = (const uint4*)(RT + (size_t)rr * NN + split * 512 + (t & 15) * 32);
    char* base = &Rs[rr * 1024];
    const int sw = (rr & 7) << 4;
#pragma unroll
    for (int u = 0; u < 4; ++u) *(uint4*)(&base[(cb + u * 16) ^ sw]) = src[u];
  }
  __syncthreads();

  const unsigned char* brow = bits + (size_t)(row0 + warp * 16 + l15) * 1024 + split * 64;
  f32x4 acc = {};
  const int rsw = (l15 & 7) << 4;
#pragma unroll
  for (int it = 0; it < 8; ++it) {
    uint2 w = *(const uint2*)(brow + it * 8);
#pragma unroll
    for (int kk = 0; kk < 2; ++kk) {
      half8 af = expand8(((kk ? w.y : w.x) >> sh8) & 0xffu);
      half8 bf = *(const half8*)(&Rs[l15 * 1024 + ((it * 128 + lq * 16 + kk * 64) ^ rsw)]);
      acc = __builtin_amdgcn_mfma_f32_16x16x32_f16(af, bf, acc, 0, 0, 0);
    }
  }
  const int r4 = lq * 4;
#pragma unroll
  for (int i = 0; i < 4; ++i) {
    int rr = row0 + warp * 16 + r4 + i;
    P2[((size_t)split * NN + rr) * DOUT + l15] = acc[i];
  }
}

__global__ __launch_bounds__(256) void k_out(const float* __restrict__ P2,
                                             const unsigned* __restrict__ sc,
                                             float* __restrict__ out) {
  float s = getscale(sc, 3, 3.0f) * getscale(sc, 2, 1.0f);
  int idx = blockIdx.x * 256 + threadIdx.x;          // float4 index < 32768
  const float4* p = (const float4*)P2;
  float4 acc = {0, 0, 0, 0};
#pragma unroll
  for (int sp = 0; sp < KS; ++sp) {
    float4 v = p[(size_t)sp * (NN * DOUT / 4) + idx];
    acc.x += v.x; acc.y += v.y; acc.z += v.z; acc.w += v.w;
  }
  acc.x *= s; acc.y *= s; acc.z *= s; acc.w *= s;
  ((float4*)out)[idx] = acc;
}

extern "C" void kernel_launch(void* const* d_in, const int* in_sizes, int n_in,
                              void* d_out, int out_size, void* d_ws, size_t ws_size,
                              hipStream_t stream) {
  const float* A  = (const float*)d_in[0];
  const float* X  = (const float*)d_in[1];
  const float* Wi = (const float*)d_in[2];
  const float* Wo = (const float*)d_in[3];
  char* ws = (char*)d_ws;
  unsigned* sc        = (unsigned*)(ws + OFF_SC);
  unsigned* part      = (unsigned*)(ws + OFF_PART);
  float* Wiq          = (float*)(ws + OFF_WIQ);
  float* Woq          = (float*)(ws + OFF_WOQ);
  _Float16* YT        = (_Float16*)(ws + OFF_YT);
  _Float16* RT        = (_Float16*)(ws + OFF_RT);
  float* hf           = (float*)(ws + OFF_HF);
  unsigned char* bits = (unsigned char*)(ws + OFF_BITS);
  float* P1           = (float*)(ws + OFF_P1);
  float* P2           = (float*)(ws + OFF_P2);
  float* out          = (float*)d_out;

  k_scales<<<242, 256, 0, stream>>>(X, Wi, Wo, part);
  k_quantW<<<1, 256, 0, stream>>>(Wi, Wo, part, sc, Wiq, Woq);
  k_bitsY<<<5120, 256, 0, stream>>>(A, X, Wiq, sc, bits, YT);
  k_gemm1<<<dim3(NN / 128, KS), 256, 0, stream>>>(bits, YT, P1);
  k_h2<<<NN * DH / 1024, 256, 0, stream>>>(P1, sc, hf);
  k_R<<<NN / 16, 256, 0, stream>>>(hf, Woq, sc, RT);
  k_gemm2<<<dim3(NN / 64, KS), 256, 0, stream>>>(bits, RT, P2);
  k_out<<<NN * DOUT / 1024, 256, 0, stream>>>(P2, sc, out);
}

// Round 6
// 125.739 us; speedup vs baseline: 1.4516x; 1.0333x over previous
//
#include <hip/hip_runtime.h>

#define NN 8192
#define DIN 128
#define DH 64
#define DOUT 16
#define KS 8             // K-split for gemm1

typedef _Float16 half8 __attribute__((ext_vector_type(8)));
typedef float f32x4 __attribute__((ext_vector_type(4)));

// workspace layout (bytes); ws ~1GB per harness fill evidence
#define OFF_SC    0u         // sc[4]: sx(raw max), -, -, maxH
#define OFF_PART  256u       // part[242]: per-block partial maxes (f32 bits); 240=Wi 241=Wo
#define OFF_YT    65536u     // f16 [64][8192]   (1 MB)   Y^T, k-dim pi-permuted
#define OFF_RT    1114112u   // f16 [16][8192]   (256 KB) R^T, k-dim pi-permuted
#define OFF_HF    1376256u   // f32 [8192][64]   (2 MB)
#define OFF_BITS  3473408u   // u8  [8192][1024] (8 MB)   A>0 bitmask, pi-permuted cols
#define OFF_P1    11862016u  // f32 [8][8192][64] (16 MB)

// pi-permutation within each 256-element group (from float4+ballot packing):
// stored position p <-> element e = 4*(p&63) + (p>>6). Applied to bits, YT, RT.
__device__ __forceinline__ int permk(int k) {
  int e = k & 255;
  return (k & ~255) | (((e & 3) << 6) | (e >> 2));
}

__device__ __forceinline__ float getscale(const unsigned* sc, int idx, float qmax) {
  float s = __uint_as_float(sc[idx]) / qmax;
  return (s == 0.0f) ? 1.0f : s;   // matches reference where(scale==0,1,scale)
}

__device__ __forceinline__ half8 expand8(unsigned bb) {  // 8 bits -> 8 f16 {0,1}
  uint4 w;
  w.x = ((bb & 1u)  ? 0x3C00u : 0u) | ((bb & 2u)   ? 0x3C000000u : 0u);
  w.y = ((bb & 4u)  ? 0x3C00u : 0u) | ((bb & 8u)   ? 0x3C000000u : 0u);
  w.z = ((bb & 16u) ? 0x3C00u : 0u) | ((bb & 32u)  ? 0x3C000000u : 0u);
  w.w = ((bb & 64u) ? 0x3C00u : 0u) | ((bb & 128u) ? 0x3C000000u : 0u);
  return __builtin_bit_cast(half8, w);
}

// K1: blocks [0,4096): binarize A via float4 + 4x ballot (16B/lane coalesced reads,
// bit order = pi permutation, free). blocks [4096,4338): abs-max partials.
__global__ __launch_bounds__(256) void k_scalesbits(const float* __restrict__ A,
                                                    const float* __restrict__ X,
                                                    const float* __restrict__ Wi,
                                                    const float* __restrict__ Wo,
                                                    unsigned char* __restrict__ bits,
                                                    unsigned* part, unsigned* sc) {
  const int t = threadIdx.x, bx = blockIdx.x;
  if (bx < 4096) {
    const int lane = t & 63, warp = t >> 6;
    const size_t wbase = ((size_t)bx * 4 + warp) * 4096;   // floats per wave
    const float4* ap = (const float4*)(A + wbase) + lane;
    unsigned char* bp = bits + (wbase >> 3);
#pragma unroll
    for (int g = 0; g < 16; ++g) {                         // 256 floats per group
      float4 v = ap[g * 64];
      unsigned long long m0 = __ballot(v.x > 0.0f);
      unsigned long long m1 = __ballot(v.y > 0.0f);
      unsigned long long m2 = __ballot(v.z > 0.0f);
      unsigned long long m3 = __ballot(v.w > 0.0f);
      unsigned long long lo = (lane & 1) ? m1 : m0;
      unsigned long long hi = (lane & 1) ? m3 : m2;
      unsigned long long word = (lane & 2) ? hi : lo;
      if (lane < 4) *(unsigned long long*)(bp + g * 32 + lane * 8) = word;
    }
    return;
  }
  __shared__ float red[256];
  const int b = bx - 4096;
  float m = 0.0f;
  if (b < 240) {
    for (int i = b * 256 + t; i < NN * DIN; i += 240 * 256) m = fmaxf(m, fabsf(X[i]));
  } else if (b == 240) {
    for (int i = t; i < DIN * DH; i += 256) m = fmaxf(m, fabsf(Wi[i]));
    if (t == 0) sc[3] = 0u;   // reset h-max for this call (ws not re-poisoned)
  } else {
    for (int i = t; i < DH * DOUT; i += 256) m = fmaxf(m, fabsf(Wo[i]));
  }
  red[t] = m; __syncthreads();
  for (int s = 128; s > 0; s >>= 1) {
    if (t < s) red[t] = fmaxf(red[t], red[t + s]);
    __syncthreads();
  }
  if (t == 0) part[b] = __float_as_uint(red[0]);
}

// K2: Y^T[j][permk(k)] = sum_n Xq_int[k][n] * Wi_int[n][j]  (exact ints, |Y|<=384)
// Wi quantized inline; sx reduced from partials in-block; block 0 publishes sc[0].
__global__ __launch_bounds__(256) void k_Y(const float* __restrict__ X,
                                           const float* __restrict__ Wi,
                                           const unsigned* __restrict__ part,
                                           unsigned* sc,
                                           _Float16* __restrict__ YT) {
  __shared__ float red[256];
  __shared__ float Xs[8][129];
  __shared__ float Ws[DIN][DH];
  const int t = threadIdx.x;
  red[t] = (t < 240) ? __uint_as_float(part[t]) : 0.0f;
  __syncthreads();
  for (int s = 128; s > 0; s >>= 1) {
    if (t < s) red[t] = fmaxf(red[t], red[t + s]);
    __syncthreads();
  }
  float sxraw = red[0];
  float sx = sxraw / 3.0f; sx = (sx == 0.0f) ? 1.0f : sx;
  float swi = __uint_as_float(part[240]); swi = (swi == 0.0f) ? 1.0f : swi;  // qmax=1
  if (blockIdx.x == 0 && t == 0) sc[0] = __float_as_uint(sxraw);
  const int k0 = blockIdx.x * 8;
  __syncthreads();   // red reuse barrier done; now fill tiles
  for (int i = t; i < 8 * DIN; i += 256) {
    int r = i >> 7, c = i & 127;
    float q = rintf(X[(size_t)(k0 + r) * DIN + c] / sx);
    Xs[r][c] = fminf(fmaxf(q, -3.0f), 3.0f);
  }
  for (int i = t; i < DIN * DH; i += 256) {
    float q = rintf(Wi[i] / swi);
    Ws[i >> 6][i & 63] = fminf(fmaxf(q, -1.0f), 1.0f);
  }
  __syncthreads();
  const int r = t & 7, jp = t >> 3, j = jp * 2;
  float a0 = 0.0f, a1 = 0.0f;
  for (int n = 0; n < DIN; ++n) {
    float xv = Xs[r][n];
    a0 = fmaf(xv, Ws[n][j], a0);
    a1 = fmaf(xv, Ws[n][j + 1], a1);
  }
  const int kp = permk(k0 + r);
  YT[(size_t)j * NN + kp]       = (_Float16)a0;   // exact integers in f16
  YT[(size_t)(j + 1) * NN + kp] = (_Float16)a1;
}

// K3: h_int = Aq @ Y. A from bits in regs (1 byte = 1 MFMA A-frag k-slice).
// BM=128, BN=64, BK=64, 4 waves m-split, KSPLIT=8, 16 iters.
__global__ __launch_bounds__(256) void k_gemm1(const unsigned char* __restrict__ bits,
                                               const _Float16* __restrict__ YT,
                                               float* __restrict__ P1) {
  __shared__ __align__(16) char Bs[64 * 128];   // f16 [64 n][64 k], XOR-16 swizzled
  const int t = threadIdx.x, lane = t & 63, warp = t >> 6;  // warp = m-tile
  const int row0 = blockIdx.x * 128;
  const int split = blockIdx.y;
  const int l15 = lane & 15, lq = lane >> 4;
  const int sh8 = lq * 8;

  f32x4 acc[2][4] = {};

  const int bn = t >> 2, bp = t & 3;
  const _Float16* bsrc = YT + (size_t)bn * NN + split * 1024 + bp * 16;
  char* bdst0 = &Bs[bn * 128 + ((bp * 32) ^ ((bn & 7) << 4))];
  char* bdst1 = &Bs[bn * 128 + ((bp * 32 + 16) ^ ((bn & 7) << 4))];

  const unsigned char* brow0 = bits + (size_t)(row0 + warp * 32 + l15) * 1024 + split * 128;
  const unsigned char* brow1 = brow0 + 16 * 1024;

  uint4 breg0 = *(const uint4*)(bsrc);
  uint4 breg1 = *(const uint4*)(bsrc + 8);

  for (int it = 0; it < 16; ++it) {
    __syncthreads();
    *(uint4*)bdst0 = breg0;
    *(uint4*)bdst1 = breg1;
    if (it < 15) {  // prefetch next B tile (BK=64 f16 elements per iteration)
      breg0 = *(const uint4*)(bsrc + (it + 1) * 64);
      breg1 = *(const uint4*)(bsrc + (it + 1) * 64 + 8);
    }
    uint2 w0 = *(const uint2*)(brow0 + it * 8);   // 64 A-bits, rows l15 / l15+16
    uint2 w1 = *(const uint2*)(brow1 + it * 8);
    __syncthreads();
#pragma unroll
    for (int kk = 0; kk < 2; ++kk) {
      half8 af0 = expand8(((kk ? w0.y : w0.x) >> sh8) & 0xffu);
      half8 af1 = expand8(((kk ? w1.y : w1.x) >> sh8) & 0xffu);
#pragma unroll
      for (int n = 0; n < 4; ++n) {
        half8 bf = *(const half8*)(&Bs[(n * 16 + l15) * 128 +
                                       ((lq * 16 + kk * 64) ^ ((l15 & 7) << 4))]);
        acc[0][n] = __builtin_amdgcn_mfma_f32_16x16x32_f16(af0, bf, acc[0][n], 0, 0, 0);
        acc[1][n] = __builtin_amdgcn_mfma_f32_16x16x32_f16(af1, bf, acc[1][n], 0, 0, 0);
      }
    }
  }
  const int r4 = lq * 4;
#pragma unroll
  for (int mf = 0; mf < 2; ++mf) {
#pragma unroll
    for (int n = 0; n < 4; ++n) {
#pragma unroll
      for (int i = 0; i < 4; ++i) {
        int rr = row0 + warp * 32 + mf * 16 + r4 + i;
        int cc = n * 16 + l15;
        P1[((size_t)split * NN + rr) * DH + cc] = acc[mf][n][i];
      }
    }
  }
}

// K4: reduce K-split partials -> h (scaled), per-block max -> atomicMax
__global__ __launch_bounds__(256) void k_h2(const float* __restrict__ P1,
                                            const unsigned* __restrict__ part,
                                            unsigned* sc, float* __restrict__ hf) {
  float sx = getscale(sc, 0, 3.0f);
  float swi = __uint_as_float(part[240]); swi = (swi == 0.0f) ? 1.0f : swi;
  float sxw = sx * swi;
  int idx = blockIdx.x * 256 + threadIdx.x;          // float4 index < 131072
  const float4* p = (const float4*)P1;
  float4 s = {0, 0, 0, 0};
#pragma unroll
  for (int sp = 0; sp < KS; ++sp) {
    float4 v = p[(size_t)sp * (NN * DH / 4) + idx];  // exact integer adds
    s.x += v.x; s.y += v.y; s.z += v.z; s.w += v.w;
  }
  s.x *= sxw; s.y *= sxw; s.z *= sxw; s.w *= sxw;
  ((float4*)hf)[idx] = s;
  float m = fmaxf(fmaxf(fabsf(s.x), fabsf(s.y)), fmaxf(fabsf(s.z), fabsf(s.w)));
  __shared__ float red[256];
  red[threadIdx.x] = m; __syncthreads();
  for (int st = 128; st > 0; st >>= 1) {
    if (threadIdx.x < st) red[threadIdx.x] = fmaxf(red[threadIdx.x], red[threadIdx.x + st]);
    __syncthreads();
  }
  if (threadIdx.x == 0) atomicMax(&sc[3], __float_as_uint(red[0]));
}

// K5: R^T[j][permk(i)] = sum_n hq_int[i][n] * Wo_int[n][j]  (|R|<=192, exact in f16)
// Wo quantized inline.
__global__ __launch_bounds__(256) void k_R(const float* __restrict__ hf,
                                           const float* __restrict__ Wo,
                                           const unsigned* __restrict__ part,
                                           const unsigned* __restrict__ sc,
                                           _Float16* __restrict__ RT) {
  __shared__ float WoS[DH][DOUT];
  float sh = getscale(sc, 3, 3.0f);
  float swo = __uint_as_float(part[241]); swo = (swo == 0.0f) ? 1.0f : swo;
  int t = threadIdx.x;
  for (int i = t; i < DH * DOUT; i += 256) {
    float q = rintf(Wo[i] / swo);
    WoS[i >> 4][i & 15] = fminf(fmaxf(q, -1.0f), 1.0f);
  }
  __syncthreads();
  int i = blockIdx.x * 16 + (t & 15), j = t >> 4;
  const float4* hp = (const float4*)(hf + (size_t)i * DH);
  float acc = 0.0f;
#pragma unroll 4
  for (int nb = 0; nb < 16; ++nb) {
    float4 h4 = hp[nb];
    float q;
    q = fminf(fmaxf(rintf(h4.x / sh), -3.0f), 3.0f); acc = fmaf(q, WoS[nb * 4 + 0][j], acc);
    q = fminf(fmaxf(rintf(h4.y / sh), -3.0f), 3.0f); acc = fmaf(q, WoS[nb * 4 + 1][j], acc);
    q = fminf(fmaxf(rintf(h4.z / sh), -3.0f), 3.0f); acc = fmaf(q, WoS[nb * 4 + 2][j], acc);
    q = fminf(fmaxf(rintf(h4.w / sh), -3.0f), 3.0f); acc = fmaf(q, WoS[nb * 4 + 3][j], acc);
  }
  RT[(size_t)j * NN + permk(i)] = (_Float16)acc;
}

// K6: out = scale * (Aq @ R), full K in-block: BM=16, 4 warps k-split 2048 each,
// RT read direct from L2 (256 KB hot), LDS cross-warp reduce, writes out directly.
__global__ __launch_bounds__(256) void k_gemm2(const unsigned char* __restrict__ bits,
                                               const _Float16* __restrict__ RT,
                                               const unsigned* __restrict__ part,
                                               const unsigned* __restrict__ sc,
                                               float* __restrict__ out) {
  __shared__ float red2[3][16][16];
  const int t = threadIdx.x, lane = t & 63, warp = t >> 6;
  const int row0 = blockIdx.x * 16;
  const int l15 = lane & 15, lq = lane >> 4;
  const int sh8 = lq * 8;

  const unsigned char* brow = bits + (size_t)(row0 + l15) * 1024 + warp * 256;
  const _Float16* rrow = RT + (size_t)l15 * NN + warp * 2048 + lq * 8;

  f32x4 acc = {};
#pragma unroll 8
  for (int it = 0; it < 32; ++it) {
    uint2 w = *(const uint2*)(brow + it * 8);
#pragma unroll
    for (int kk = 0; kk < 2; ++kk) {
      half8 af = expand8(((kk ? w.y : w.x) >> sh8) & 0xffu);
      half8 bf = *(const half8*)(rrow + it * 64 + kk * 32);
      acc = __builtin_amdgcn_mfma_f32_16x16x32_f16(af, bf, acc, 0, 0, 0);
    }
  }
  if (warp > 0) {
#pragma unroll
    for (int i = 0; i < 4; ++i) red2[warp - 1][lq * 4 + i][l15] = acc[i];
  }
  __syncthreads();
  if (warp == 0) {
    float sh = getscale(sc, 3, 3.0f);
    float swo = __uint_as_float(part[241]); swo = (swo == 0.0f) ? 1.0f : swo;
    float s = sh * swo;
#pragma unroll
    for (int i = 0; i < 4; ++i) {
      int r = lq * 4 + i;
      float v = acc[i] + red2[0][r][l15] + red2[1][r][l15] + red2[2][r][l15];
      out[(size_t)(row0 + r) * DOUT + l15] = v * s;
    }
  }
}

extern "C" void kernel_launch(void* const* d_in, const int* in_sizes, int n_in,
                              void* d_out, int out_size, void* d_ws, size_t ws_size,
                              hipStream_t stream) {
  const float* A  = (const float*)d_in[0];
  const float* X  = (const float*)d_in[1];
  const float* Wi = (const float*)d_in[2];
  const float* Wo = (const float*)d_in[3];
  char* ws = (char*)d_ws;
  unsigned* sc        = (unsigned*)(ws + OFF_SC);
  unsigned* part      = (unsigned*)(ws + OFF_PART);
  _Float16* YT        = (_Float16*)(ws + OFF_YT);
  _Float16* RT        = (_Float16*)(ws + OFF_RT);
  float* hf           = (float*)(ws + OFF_HF);
  unsigned char* bits = (unsigned char*)(ws + OFF_BITS);
  float* P1           = (float*)(ws + OFF_P1);
  float* out          = (float*)d_out;

  k_scalesbits<<<4338, 256, 0, stream>>>(A, X, Wi, Wo, bits, part, sc);
  k_Y<<<1024, 256, 0, stream>>>(X, Wi, part, sc, YT);
  k_gemm1<<<dim3(NN / 128, KS), 256, 0, stream>>>(bits, YT, P1);
  k_h2<<<NN * DH / 1024, 256, 0, stream>>>(P1, part, sc, hf);
  k_R<<<NN / 16, 256, 0, stream>>>(hf, Wo, part, sc, RT);
  k_gemm2<<<NN / 16, 256, 0, stream>>>(bits, RT, part, sc, out);
}